// Round 12
// baseline (243.323 us; speedup 1.0000x reference)
//
#include <hip/hip_runtime.h>
#include <hip/hip_bf16.h>
#include <math.h>

#define NDIM 768
#define NHEADS 12
#define HD 64
#define SEQ 1024
#define BATCH 8
#define MROWS (BATCH * SEQ)          // 8192
#define SQRT_DIM 27.712812921102035f // 1/SCALE_PARAM_INIT
#define LOG2E 1.4426950408889634f

typedef unsigned short u16;
typedef unsigned int u32;
typedef __attribute__((ext_vector_type(8))) short short8;   // 8 bf16 = 4 VGPRs
typedef __attribute__((ext_vector_type(4))) short bf16x4;   // 4 bf16 = 2 VGPRs
typedef __attribute__((ext_vector_type(4))) float f32x4;
typedef __attribute__((ext_vector_type(16))) float f32x16;

#define MFMA16(a, b, c) __builtin_amdgcn_mfma_f32_16x16x32_bf16(a, b, c, 0, 0, 0)
#define MFMA32(a, b, c) __builtin_amdgcn_mfma_f32_32x32x16_bf16(a, b, c, 0, 0, 0)

#if __has_builtin(__builtin_amdgcn_exp2f)
#define EXP2(x) __builtin_amdgcn_exp2f(x)
#else
#define EXP2(x) exp2f(x)
#endif

__device__ inline u16 f2bf(float f) {
    __hip_bfloat16 h = __float2bfloat16(f);
    return *reinterpret_cast<u16*>(&h);
}

// RNE round a,b to bf16 and pack into one u32 (a = low half). No NaN check —
// callers guarantee finite inputs.
__device__ inline u32 rne_pack(float a, float b) {
    u32 ua = __builtin_bit_cast(u32, a), ub = __builtin_bit_cast(u32, b);
    ua = (ua + 0x7fffu + ((ua >> 16) & 1u)) >> 16;
    ub = (ub + 0x7fffu + ((ub >> 16) & 1u)) >> 16;
    return (ub << 16) | ua;
}

// async 16B global->LDS. LDS dest is wave-uniform base; HW adds lane*16.
__device__ inline void gl2lds16(const void* g, void* l) {
    __builtin_amdgcn_global_load_lds((const __attribute__((address_space(1))) void*)g,
                                     (__attribute__((address_space(3))) void*)l, 16, 0, 0);
}

// ---------------------------------------------------------------------------
// One fused cast kernel: x (6144 blocks) + Wq/Wk/Wv -> Wqkv, Wo -> Wob.
// ---------------------------------------------------------------------------
__global__ __launch_bounds__(256) void castall(const float* __restrict__ x,
                                               const float* __restrict__ Wq,
                                               const float* __restrict__ Wk,
                                               const float* __restrict__ Wv,
                                               const float* __restrict__ Wo,
                                               u16* __restrict__ xb,
                                               u16* __restrict__ Wqkv,
                                               u16* __restrict__ Wob) {
    const int WB = (NDIM * NDIM) / 1024; // 576 blocks per weight
    int blk = blockIdx.x;
    const float* s;
    u16* d;
    int base;
    if (blk < 6144) {
        s = x; d = xb; base = blk * 1024;
    } else {
        int wsel = (blk - 6144) / WB, r = (blk - 6144) % WB;
        base = r * 1024;
        if (wsel == 0)      { s = Wq; d = Wqkv; }
        else if (wsel == 1) { s = Wk; d = Wqkv + NDIM * NDIM; }
        else if (wsel == 2) { s = Wv; d = Wqkv + 2 * NDIM * NDIM; }
        else                { s = Wo; d = Wob; }
    }
    int i = base + threadIdx.x * 4;
    float4 v = *(const float4*)(s + i);
    uint2 o = make_uint2(rne_pack(v.x, v.y), rne_pack(v.z, v.w));
    *(uint2*)(d + i) = o;
}

// ---------------------------------------------------------------------------
// bf16 MFMA GEMM: C = A[M,768] @ B[N,768]^T, fp32 accum. Tile = TM x 128,
// 4 waves (2x2; each wave TM/2 rows x 64 cols), double-buffered BK=32.
// A staged via gl2lds with the cacheline-dense slot swizzle (16 fully-used
// lines per span); B (weights) is NOT staged: every row-stripe block would
// re-read the same L2-resident tile, so the LDS round-trip only duplicated
// L2 — B fragments load straight to registers (b128, 16 rows x full 64B
// lines), software-pipelined one iter ahead (bnext issued after the barrier,
// drained by the next barrier's vmcnt(0)). Halves GEMM LDS traffic.
// 1D grid, XCD-stripe swizzle. EPI 0: fp32 C. EPI 2: fused QKV epilogue.
// TM=128 for QKV (1152 blocks); TM=64 for Wo (768 blocks, fixes 1.5/CU tail).
// ---------------------------------------------------------------------------
template <int EPI, int TM>
__global__ __launch_bounds__(256) void gemm_bf16(const u16* __restrict__ A,
                                                 const u16* __restrict__ B,
                                                 void* __restrict__ C, int N,
                                                 const float* __restrict__ s_qk,
                                                 u16* __restrict__ Qdst,
                                                 u16* __restrict__ Kdst,
                                                 int NX) {
    constexpr int K = NDIM;
    constexpr int NKT = K / 32;    // 24 K-tiles
    constexpr int MI = TM / 32;    // acc row-tiles per wave (4 or 2)
    __shared__ __align__(16) u16 As[2][TM * 32];
    const int t = threadIdx.x;
    const int wave = t >> 6, lane = t & 63;
    const int quad = lane >> 4, l16 = lane & 15;
    const int wx = (wave & 1) * 64, wy = (wave >> 1) * (TM / 2);
    const int blk = blockIdx.x;
    const int xcd = blk & 7, local = blk >> 3;
    constexpr int MT_PER_XCD = (MROWS / TM) / 8;
    const int bm = (xcd * MT_PER_XCD + local / NX) * TM;
    const int bn = (local % NX) * 128;

    f32x4 acc[MI][4];
#pragma unroll
    for (int i = 0; i < MI; ++i)
#pragma unroll
        for (int j = 0; j < 4; ++j) acc[i][j] = (f32x4){0.f, 0.f, 0.f, 0.f};

    // A staging lane->global mapping (inverse of the slot swizzle)
    const int srl = lane >> 2;                        // row within 16-row span
    const int skc = (lane & 3) ^ ((lane >> 3) & 3);   // chunk 0..3
    auto stageA = [&](int k0, int bsel) {
#pragma unroll
        for (int it = 0; it < TM / 64; ++it) {
            const int cb = it * 256 + wave * 64;      // span base (wave-uniform)
            const int row = (cb >> 6) * 16 + srl;
            gl2lds16(A + (size_t)(bm + row) * K + k0 + skc * 8,
                     (char*)As[bsel] + cb * 16);
        }
    };
    // B fragment loader (direct from global/L2, B-operand layout)
    auto loadB = [&](int k0, short8* bf) {
#pragma unroll
        for (int j = 0; j < 4; ++j)
            bf[j] = *(const short8*)(B + (size_t)(bn + wx + j * 16 + l16) * K +
                                     k0 + quad * 8);
    };
    // fragment-read swizzle piece
    const int fxor = (l16 >> 1) & 3;

    short8 bcur[4], bnext[4];
    stageA(0, 0);
    loadB(0, bcur);
#pragma unroll
    for (int kt = 0; kt < NKT; ++kt) {
        __syncthreads(); // drains tile-kt A staging + bcur loads
        if (kt + 1 < NKT) {
            stageA((kt + 1) * 32, (kt + 1) & 1);
            loadB((kt + 1) * 32, bnext);
        }
        const int b = kt & 1;
        short8 af[MI];
#pragma unroll
        for (int i = 0; i < MI; ++i)
            af[i] = *(const short8*)&As[b][
                ((((wy >> 4) + i) * 64 + l16 * 4 + (quad ^ fxor)) * 8)];
#pragma unroll
        for (int i = 0; i < MI; ++i)
#pragma unroll
            for (int j = 0; j < 4; ++j) acc[i][j] = MFMA16(af[i], bcur[j], acc[i][j]);
#pragma unroll
        for (int j = 0; j < 4; ++j) bcur[j] = bnext[j];
    }

    if constexpr (EPI == 0) {
#pragma unroll
        for (int i = 0; i < MI; ++i)
#pragma unroll
            for (int j = 0; j < 4; ++j)
#pragma unroll
                for (int r = 0; r < 4; ++r) {
                    const int row = bm + wy + i * 16 + quad * 4 + r;
                    const int col = bn + wx + j * 16 + l16;
                    ((float*)C)[(size_t)row * N + col] = acc[i][j][r];
                }
    } else {
        const int cg = (bn + wx) >> 6; // 0..35
        if (cg >= 2 * NHEADS) {
            // V path: transposed bf16 write into Vt = C
            const int h = cg - 2 * NHEADS;
#pragma unroll
            for (int i = 0; i < MI; ++i)
#pragma unroll
                for (int j = 0; j < 4; ++j)
#pragma unroll
                    for (int r = 0; r < 4; ++r) {
                        const int row = bm + wy + i * 16 + quad * 4 + r; // token
                        const int dd = j * 16 + l16;
                        const int b = row >> 10, n = row & 1023;
                        ((u16*)C)[(((size_t)(b * NHEADS + h) * HD + dd) << 10) + n] =
                            f2bf(acc[i][j][r]);
                    }
        } else {
            const bool isq = cg < NHEADS;
            const int h = isq ? cg : cg - NHEADS;
            u16* dst = isq ? Qdst : Kdst;
            const float ex = isq ? 8.f * LOG2E : 1.f;
            float sq[4];
#pragma unroll
            for (int j = 0; j < 4; ++j)
                sq[j] = s_qk[h * HD + j * 16 + l16] * SQRT_DIM * ex;
#pragma unroll
            for (int i = 0; i < MI; ++i)
#pragma unroll
                for (int r = 0; r < 4; ++r) {
                    float ss = 0.f;
#pragma unroll
                    for (int j = 0; j < 4; ++j) ss += acc[i][j][r] * acc[i][j][r];
                    ss += __shfl_xor(ss, 1, 64);
                    ss += __shfl_xor(ss, 2, 64);
                    ss += __shfl_xor(ss, 4, 64);
                    ss += __shfl_xor(ss, 8, 64);
                    float inv = 1.f / fmaxf(sqrtf(ss), 1e-6f);
                    const int row = bm + wy + i * 16 + quad * 4 + r;
                    const int b = row >> 10, tok = row & 1023;
                    u16* o = dst + ((size_t)(b * NHEADS + h) * SEQ + tok) * HD;
#pragma unroll
                    for (int j = 0; j < 4; ++j)
                        o[j * 16 + l16] = f2bf(acc[i][j][r] * sq[j] * inv);
                }
        }
    }
}

// ---------------------------------------------------------------------------
// MFMA flash attention, 32x32x16, no-max softmax. 256 threads = 4 waves;
// each wave owns 32 queries -> block = 128 queries; streams 64-key tiles.
//   S^T = MFMA(A=K, B=Q); O^T = MFMA(A=V^T, B=P).
// K/V LDS slot swizzle S(r,c8) = (r>>3)*64 + (r&7)*8 + (c8 ^ (r&7)):
// 16 fully-used cachelines per gl2lds span; fragment reads bank-spread.
// P buffer: row stride 64 u16, XOR-swizzled 8B units -> conflict-free b64.
// Softmax: raw v_exp_f32, manual RNE pair-pack, raw-fp32 l accumulation.
// ---------------------------------------------------------------------------
__global__ __launch_bounds__(256) void attn_mfma(const u16* __restrict__ Qh,
                                                 const u16* __restrict__ Kh,
                                                 const u16* __restrict__ Vt,
                                                 u16* __restrict__ AO) {
    __shared__ __align__(16) u16 Ks[512 * 8];
    __shared__ __align__(16) u16 Vs[512 * 8];
    __shared__ __align__(16) u16 Ps[4 * 32 * 64]; // [wave][qrow][64], swizzled

    const int t = threadIdx.x;
    const int wave = t >> 6, lane = t & 63;
    const int l31 = lane & 31, half = lane >> 5;
    const int b = blockIdx.z, h = blockIdx.y, q0 = blockIdx.x * 128;
    const int bh = b * NHEADS + h;
    const u16* Kb = Kh + (size_t)bh * SEQ * HD;
    const u16* Vb = Vt + (size_t)bh * HD * SEQ;
    const int qb = q0 + wave * 32;
    const int pbase = wave * 2048 + l31 * 64; // this lane's P row (u16 idx)
    const int sw = (l31 & 15);                // XOR key for 8B units

    // Q fragments (B-operand: n = query = l31, k = tt*16 + half*8 + j)
    short8 qf[4];
#pragma unroll
    for (int tt = 0; tt < 4; ++tt)
        qf[tt] = *(const short8*)(Qh + ((size_t)bh * SEQ + qb + l31) * HD +
                                  tt * 16 + half * 8);

    f32x16 o[2]; // [d-tile]
#pragma unroll
    for (int dt = 0; dt < 2; ++dt)
#pragma unroll
        for (int r = 0; r < 16; ++r) o[dt][r] = 0.f;
    float lp = 0.f;

    // staging lane->global mapping (inverse of slot swizzle)
    const int arl = lane >> 3;            // row within 8-row span
    const int acc8 = (lane & 7) ^ arl;    // chunk 0..7
    // fragment-read bank spread piece
    const int fx8 = l31 & 7;

    for (int j0 = 0; j0 < SEQ; j0 += 64) {
        __syncthreads();
#pragma unroll
        for (int it = 0; it < 2; ++it) {
            const int cb = it * 256 + wave * 64; // span base, wave-uniform
            const int r0 = (cb >> 6) * 8 + arl;  // row 0..63
            gl2lds16(Kb + (size_t)(j0 + r0) * HD + acc8 * 8, (char*)Ks + cb * 16);
            gl2lds16(Vb + (size_t)r0 * SEQ + j0 + acc8 * 8, (char*)Vs + cb * 16);
        }
        asm volatile("s_waitcnt vmcnt(0)" ::: "memory");
        __syncthreads();

        // ---- S^T phase: 64 keys x 32 queries ----
#pragma unroll
        for (int kt = 0; kt < 2; ++kt) {
            f32x16 sa;
#pragma unroll
            for (int r = 0; r < 16; ++r) sa[r] = 0.f;
#pragma unroll
            for (int tt = 0; tt < 4; ++tt) {
                short8 kf = *(const short8*)&Ks[
                    (((kt * 4 + (l31 >> 3)) * 64) + fx8 * 8 +
                     ((2 * tt + half) ^ fx8)) * 8];
                sa = MFMA32(kf, qf[tt], sa);
            }
            // raw exp2 (log2-domain, bounded), RNE pair-pack, raw-l, b64 write
#pragma unroll
            for (int rg = 0; rg < 4; ++rg) {
                float p0 = EXP2(sa[rg * 4 + 0]);
                float p1 = EXP2(sa[rg * 4 + 1]);
                float p2 = EXP2(sa[rg * 4 + 2]);
                float p3 = EXP2(sa[rg * 4 + 3]);
                lp += (p0 + p1) + (p2 + p3);
                uint2 pk = make_uint2(rne_pack(p0, p1), rne_pack(p2, p3));
                const int u = kt * 8 + rg * 2 + half; // logical 8B unit
                *(uint2*)&Ps[pbase + (u ^ sw) * 4] = pk;
            }
        }

        // ---- PV phase: O^T += V^T @ P (own-wave P; DS pipe is in-order) ----
#pragma unroll
        for (int k2 = 0; k2 < 4; ++k2) {
            const int u0 = k2 * 4 + half * 2;
            bf16x4 lo = *(const bf16x4*)&Ps[pbase + ((u0 + 0) ^ sw) * 4];
            bf16x4 hi = *(const bf16x4*)&Ps[pbase + ((u0 + 1) ^ sw) * 4];
            short8 pf = __builtin_shufflevector(lo, hi, 0, 1, 2, 3, 4, 5, 6, 7);
#pragma unroll
            for (int dt = 0; dt < 2; ++dt) {
                short8 vf = *(const short8*)&Vs[
                    (((dt * 4 + (l31 >> 3)) * 64) + fx8 * 8 +
                     ((2 * k2 + half) ^ fx8)) * 8];
                o[dt] = MFMA32(vf, pf, o[dt]);
            }
        }
    }

    // final l reduction (halves hold disjoint key subsets) and output
    const float invl = 1.f / (lp + __shfl_xor(lp, 32, 64));
    u16* ob = AO + (size_t)(b * SEQ + qb + l31) * NDIM + h * HD;
#pragma unroll
    for (int dt = 0; dt < 2; ++dt)
#pragma unroll
        for (int rg = 0; rg < 4; ++rg) {
            bf16x4 ok = {(short)f2bf(o[dt][rg * 4 + 0] * invl),
                         (short)f2bf(o[dt][rg * 4 + 1] * invl),
                         (short)f2bf(o[dt][rg * 4 + 2] * invl),
                         (short)f2bf(o[dt][rg * 4 + 3] * invl)};
            *(bf16x4*)(ob + dt * 32 + rg * 8 + half * 4) = ok;
        }
}

// ---------------------------------------------------------------------------
extern "C" void kernel_launch(void* const* d_in, const int* in_sizes, int n_in,
                              void* d_out, int out_size, void* d_ws, size_t ws_size,
                              hipStream_t stream) {
    const float* x    = (const float*)d_in[0];
    const float* Wq   = (const float*)d_in[1];
    const float* Wk   = (const float*)d_in[2];
    const float* Wv   = (const float*)d_in[3];
    const float* Wo   = (const float*)d_in[4];
    const float* s_qk = (const float*)d_in[5];
    float* out = (float*)d_out;

    char* w = (char*)d_ws;
    const size_t TE = (size_t)MROWS * NDIM;
    u16* xb   = (u16*)w;                    w += TE * 2;
    u16* Wqkv = (u16*)w;                    w += (size_t)3 * NDIM * NDIM * 2;
    u16* Wob  = (u16*)w;                    w += (size_t)NDIM * NDIM * 2;
    u16* Qh   = (u16*)w;                    w += TE * 2;
    u16* Kh   = (u16*)w;                    w += TE * 2;
    u16* Vt   = (u16*)w;                    w += TE * 2;
    u16* ao   = (u16*)w;

    castall<<<6144 + 4 * 576, 256, 0, stream>>>(x, Wq, Wk, Wv, Wo, xb, Wqkv, Wob);

    // Fused QKV projection (TM=128): NX = 2304/128 = 18, 1152 blocks
    gemm_bf16<2, 128><<<18 * 64, 256, 0, stream>>>(
        xb, Wqkv, (void*)Vt, 2304, s_qk, Qh, Kh, 18);

    attn_mfma<<<dim3(SEQ / 128, NHEADS, BATCH), 256, 0, stream>>>(Qh, Kh, Vt, ao);

    // Output projection (TM=64): NX = 6, 128 M-tiles -> 768 blocks
    gemm_bf16<0, 64><<<6 * 128, 256, 0, stream>>>(
        ao, Wob, out, NDIM, nullptr, nullptr, nullptr, 6);
}